// Round 10
// baseline (233.940 us; speedup 1.0000x reference)
//
#include <hip/hip_runtime.h>
#include <hip/hip_fp16.h>
#include <cstdint>
#include <cstddef>

#define N_NODES 100000
#define E_EDGES 6400000
#define E_TOT   (E_EDGES + N_NODES)
#define IN_CH   128
#define NHID    16              // HEADS*HID
#define BSHIFT  9               // 512 dsts per bucket
#define BSZ     512
#define NBUCK   196             // ceil(100000/512)
#define CHUNK   6144            // edges per k_bin block
#define BCAP    48              // LDS staging capacity per bucket (mean 31.3)
#define NCHUNK  ((E_TOT + CHUNK - 1) / CHUNK)   // 1058

// ---------------- detection: int64 vs int32 edge_index ----------------
__global__ void k_detect(const int* __restrict__ edge, int* __restrict__ flag) {
    if (blockIdx.x == 0 && threadIdx.x == 0) {
        int odd_or = 0;
        for (int i = 0; i < 64; i++) odd_or |= edge[2 * i + 1];
        flag[0] = (odd_or == 0) ? 1 : 0;   // 1 => data is int64 little-endian
    }
}

// ------- layer-1 node features: h16 rows + split alpha arrays ---------
__global__ __launch_bounds__(256) void k_gemm1(
        const float* __restrict__ x, const float* __restrict__ W1,
        const float* __restrict__ a_src1, const float* __restrict__ a_dst1,
        __half* __restrict__ h16, float* __restrict__ asrc,
        float* __restrict__ adst) {
    __shared__ __align__(16) float sW[IN_CH * NHID];   // 8 KB
    __shared__ __align__(16) float sx[16][132];        // padded stride
    __shared__ float sh[16][17];
    int t = threadIdx.x;
    int r = t >> 4, c = t & 15;
    int row = blockIdx.x * 16 + r;

    const float4* W4 = (const float4*)W1;
    ((float4*)sW)[t] = W4[t];
    ((float4*)sW)[t + 256] = W4[t + 256];

    if (row < N_NODES) {
        const float4* xr = (const float4*)(x + (size_t)row * IN_CH);
        float4 v0 = xr[c];
        float4 v1 = xr[c + 16];
        *(float4*)&sx[r][4 * c] = v0;
        *(float4*)&sx[r][64 + 4 * c] = v1;
    }
    __syncthreads();

    float acc = 0.f;
    if (row < N_NODES) {
        #pragma unroll 16
        for (int k = 0; k < IN_CH; k++) acc = fmaf(sx[r][k], sW[k * NHID + c], acc);
        h16[(size_t)row * NHID + c] = __float2half(acc);
    }
    sh[r][c] = acc;
    __syncthreads();

    if (row < N_NODES && c < 4) {
        int h = c & 1;
        const float* av = (c >= 2) ? a_dst1 : a_src1;
        float s = 0.f;
        #pragma unroll
        for (int q = 0; q < 8; q++) s = fmaf(sh[r][h * 8 + q], av[h * 8 + q], s);
        if (c < 2) asrc[2 * (size_t)row + c] = s;
        else       adst[2 * (size_t)row + (c - 2)] = s;
    }
}

// --- per-chunk 196-bucket histogram; int4-vectorized edge reads -------
__global__ __launch_bounds__(256) void k_ccount(const int* __restrict__ edge,
                                                const int* __restrict__ flag,
                                                int* __restrict__ ccnt) {
    __shared__ int sc[NBUCK];
    int m64 = flag[0];
    int t = threadIdx.x;
    for (int i = t; i < NBUCK; i += 256) sc[i] = 0;
    __syncthreads();
    size_t c0 = (size_t)blockIdx.x * CHUNK;
    size_t cend = c0 + CHUNK; if (cend > E_TOT) cend = E_TOT;
    size_t ee = (cend < (size_t)E_EDGES) ? cend : (size_t)E_EDGES;

    if (m64) {
        const int4* dp = (const int4*)(edge + 2 * (size_t)E_EDGES);
        for (size_t i = c0 + 2 * t; i < ee; i += 512) {
            int4 v = dp[i >> 1];                 // dsts of edges i, i+1
            atomicAdd(&sc[v.x >> BSHIFT], 1);
            if (i + 1 < ee) atomicAdd(&sc[v.z >> BSHIFT], 1);
        }
    } else {
        const int4* dp = (const int4*)(edge + (size_t)E_EDGES);
        for (size_t i = c0 + 4 * t; i < ee; i += 1024) {
            int4 v = dp[i >> 2];                 // dsts of edges i..i+3
            atomicAdd(&sc[v.x >> BSHIFT], 1);
            if (i + 1 < ee) atomicAdd(&sc[v.y >> BSHIFT], 1);
            if (i + 2 < ee) atomicAdd(&sc[v.z >> BSHIFT], 1);
            if (i + 3 < ee) atomicAdd(&sc[v.w >> BSHIFT], 1);
        }
    }
    size_t sl0 = (c0 > (size_t)E_EDGES) ? c0 : (size_t)E_EDGES;
    for (size_t i = sl0 + t; i < cend; i += 256) {
        int d = (int)(i - E_EDGES);              // self-loop: no memory read
        atomicAdd(&sc[d >> BSHIFT], 1);
    }
    __syncthreads();
    for (int i = t; i < NBUCK; i += 256)
        ccnt[(size_t)blockIdx.x * NBUCK + i] = sc[i];
}

// --- per-bucket exclusive scan over chunks: exact per-chunk bases -----
__global__ __launch_bounds__(256) void k_cscan(int* __restrict__ ccnt,
                                               int* __restrict__ bcnt) {
    __shared__ int sd[256];
    __shared__ int carry;
    int b = blockIdx.x, t = threadIdx.x;
    if (t == 0) carry = 0;
    __syncthreads();
    for (int base = 0; base < NCHUNK; base += 256) {
        int c = base + t;
        int v = (c < NCHUNK) ? ccnt[(size_t)c * NBUCK + b] : 0;
        sd[t] = v;
        __syncthreads();
        for (int ofs = 1; ofs < 256; ofs <<= 1) {
            int a = sd[t];
            int bb = (t >= ofs) ? sd[t - ofs] : 0;
            __syncthreads();
            sd[t] = a + bb;
            __syncthreads();
        }
        if (c < NCHUNK) ccnt[(size_t)c * NBUCK + b] = sd[t] - v + carry;
        __syncthreads();
        if (t == 255) carry += sd[255];
        __syncthreads();
    }
    if (t == 0) bcnt[b] = carry;
}

// ---------------- tiny scan over 196 bucket totals ----------------
__global__ void k_bscan(const int* __restrict__ bcnt, int* __restrict__ bbase) {
    __shared__ int sd[256];
    int t = threadIdx.x;
    int v = (t < NBUCK) ? bcnt[t] : 0;
    sd[t] = v;
    __syncthreads();
    for (int ofs = 1; ofs < 256; ofs <<= 1) {
        int a = sd[t];
        int b = (t >= ofs) ? sd[t - ofs] : 0;
        __syncthreads();
        sd[t] = a + b;
        __syncthreads();
    }
    if (t < NBUCK) bbase[t] = sd[t] - v;        // exclusive
    if (t == NBUCK) bbase[NBUCK] = sd[NBUCK - 1];
}

// ------ binning with precomputed exact slots: ZERO global atomics -----
__global__ __launch_bounds__(256) void k_bin(const int* __restrict__ edge,
                                             const int* __restrict__ flag,
                                             const int* __restrict__ ccnt,
                                             const int* __restrict__ bbase,
                                             unsigned* __restrict__ staged) {
    __shared__ unsigned lbin[NBUCK][BCAP];   // 37.6 KB -> 4 blocks/CU
    __shared__ int lcnt[NBUCK];
    __shared__ int lbase[NBUCK];
    int m64 = flag[0];
    int t = threadIdx.x;
    int g = t >> 4, lane = t & 15;

    size_t c0 = (size_t)blockIdx.x * CHUNK;
    if (c0 >= E_TOT) return;
    size_t cend = c0 + CHUNK; if (cend > E_TOT) cend = E_TOT;
    size_t ee = (cend < (size_t)E_EDGES) ? cend : (size_t)E_EDGES;

    for (int i = t; i < NBUCK; i += 256) {
        lcnt[i] = 0;
        lbase[i] = bbase[i] + ccnt[(size_t)blockIdx.x * NBUCK + i];
    }
    __syncthreads();

    auto put = [&](int s, int d) {
        int b = d >> BSHIFT;
        unsigned v = (unsigned)s | ((unsigned)(d & (BSZ - 1)) << 17);
        int idx = atomicAdd(&lcnt[b], 1);
        if (idx < BCAP) lbin[b][idx] = v;
        else            staged[lbase[b] + idx] = v;   // exact slot, no atomic
    };

    if (m64) {
        const int4* sp = (const int4*)edge;
        const int4* dp = (const int4*)(edge + 2 * (size_t)E_EDGES);
        for (size_t i = c0 + 2 * t; i < ee; i += 512) {
            int4 sv = sp[i >> 1];
            int4 dv = dp[i >> 1];
            put(sv.x, dv.x);
            if (i + 1 < ee) put(sv.z, dv.z);
        }
    } else {
        const int4* sp = (const int4*)edge;
        const int4* dp = (const int4*)(edge + (size_t)E_EDGES);
        for (size_t i = c0 + 4 * t; i < ee; i += 1024) {
            int4 sv = sp[i >> 2];
            int4 dv = dp[i >> 2];
            put(sv.x, dv.x);
            if (i + 1 < ee) put(sv.y, dv.y);
            if (i + 2 < ee) put(sv.z, dv.z);
            if (i + 3 < ee) put(sv.w, dv.w);
        }
    }
    size_t sl0 = (c0 > (size_t)E_EDGES) ? c0 : (size_t)E_EDGES;
    for (size_t i = sl0 + t; i < cend; i += 256) {
        int d = (int)(i - E_EDGES);
        put(d, d);
    }
    __syncthreads();
    // cooperative coalesced flush of the LDS-staged majority
    for (int b = g; b < NBUCK; b += 16) {
        int n = min(lcnt[b], BCAP);
        if (!n) continue;
        int pos = lbase[b];
        for (int i = lane; i < n; i += 16) staged[pos + i] = lbin[b][i];
    }
}

// -- counting sort -> 8B CSR records {half2(p0,p1), src}; fused exp ----
// 2 blocks/bucket (edge-range split). adst staged in LDS (bucket-local);
// asrc gathered from L2-resident 0.8MB array; exp computed ONCE per edge.
__global__ __launch_bounds__(1024) void k_sort(const unsigned* __restrict__ staged,
                                               const int* __restrict__ bbase,
                                               const float* __restrict__ asrc,
                                               const float* __restrict__ adst,
                                               uint2* __restrict__ csr8,
                                               int* __restrict__ offs) {
    __shared__ int hist[BSZ];
    __shared__ int histlo[BSZ];
    __shared__ int lcur[BSZ];
    __shared__ float2 sadp[BSZ];   // 4 KB
    int bkt = blockIdx.x >> 1, p = blockIdx.x & 1;
    int t = threadIdx.x;
    int beg = bbase[bkt], end = bbase[bkt + 1];
    int mid = beg + ((end - beg + 1) >> 1);
    int dbase = bkt << BSHIFT;

    if (t < BSZ) { hist[t] = 0; histlo[t] = 0; }
    for (int i = t; i < BSZ; i += 1024) {
        int dd = dbase + i;
        sadp[i] = (dd < N_NODES) ? ((const float2*)adst)[dd] : make_float2(0.f, 0.f);
    }
    __syncthreads();
    for (int e = beg + t; e < end; e += 1024) {
        int dl = staged[e] >> 17;
        atomicAdd(&hist[dl], 1);
        if (e < mid) atomicAdd(&histlo[dl], 1);
    }
    __syncthreads();

    int myv = (t < BSZ) ? hist[t] : 0;
    __syncthreads();
    for (int ofs = 1; ofs < BSZ; ofs <<= 1) {
        int a = 0, b = 0;
        if (t < BSZ) { a = hist[t]; b = (t >= ofs) ? hist[t - ofs] : 0; }
        __syncthreads();
        if (t < BSZ) hist[t] = a + b;
        __syncthreads();
    }
    if (t < BSZ) {
        int excl = hist[t] - myv;
        lcur[t] = excl + (p ? histlo[t] : 0);
        if (p == 0) {
            int dd = dbase + t;
            if (dd < N_NODES) offs[dd] = beg + excl;
        }
    }
    if (bkt == NBUCK - 1 && p == 0 && t == 0) offs[N_NODES] = E_TOT;
    __syncthreads();

    int lo = p ? mid : beg;
    int hi = p ? end : mid;
    for (int e = lo + t; e < hi; e += 1024) {
        unsigned v = staged[e];
        int s  = (int)(v & 0x1FFFFu);
        int dl = (int)(v >> 17);
        float2 asp = ((const float2*)asrc)[s];
        float a0 = asp.x + sadp[dl].x; a0 = (a0 > 0.f) ? a0 : 0.2f * a0;
        float a1 = asp.y + sadp[dl].y; a1 = (a1 > 0.f) ? a1 : 0.2f * a1;
        __half2 hp = __floats2half2_rn(__expf(a0), __expf(a1));
        int pos = atomicAdd(&lcur[dl], 1);
        csr8[beg + pos] = make_uint2(*(unsigned*)&hp, (unsigned)s);
    }
}

// --- layer-1 edge pass: pair-lane (2 lanes/edge), 6-deep pipeline -----
// Lane pair loads the 32B h row via two 16B loads in the SAME instruction
// (same 64B line -> 1 TA transaction); p comes from csr8 (coalesced).
// No asrc gather, no exp. Gather set = 3.2MB h16: L2-resident.
__global__ __launch_bounds__(256) void k_edge1(
        const int* __restrict__ offs, const uint2* __restrict__ csr8,
        const __half* __restrict__ h16,
        const float* __restrict__ b1, const float* __restrict__ W2,
        float* __restrict__ h2out) {
    __shared__ float sacc[256][9];   // 9 KB, padded
    int t = threadIdx.x;
    int lane = t & 15;
    int g = t >> 4;
    int d = blockIdx.x * 16 + g;
    if (d >= N_NODES) return;

    int sub = lane & 1;        // 0: head0/ch0-7, 1: head1/ch8-15
    int pr  = lane >> 1;       // pair index 0..7
    int beg = offs[d], end = offs[d + 1];

    float acc[8];
    #pragma unroll
    for (int c = 0; c < 8; c++) acc[c] = 0.f;
    float den = 0.f;

    auto loadslot = [&](int ee, uint2& ps, float4& hv) {
        if (ee < end) {
            ps = csr8[ee];
            hv = *(const float4*)(h16 + (size_t)ps.y * NHID + sub * 8);
        }
    };
    auto consume = [&](const uint2& ps, const float4& hv) {
        __half2 hp = *(const __half2*)&ps.x;
        float pw = sub ? __half2float(hp.y) : __half2float(hp.x);
        den += pw;
        const __half2* hh = (const __half2*)&hv;
        #pragma unroll
        for (int q = 0; q < 4; q++) {
            float2 f = __half22float2(hh[q]);
            acc[2 * q]     = fmaf(pw, f.x, acc[2 * q]);
            acc[2 * q + 1] = fmaf(pw, f.y, acc[2 * q + 1]);
        }
    };

    uint2 psA{}, psB{}, psC{}, psD{}, psE{}, psF{};
    float4 z4 = make_float4(0.f, 0.f, 0.f, 0.f);
    float4 hA = z4, hB = z4, hC = z4, hD = z4, hE = z4, hF = z4;

    int e = beg + pr;
    loadslot(e,      psA, hA);
    loadslot(e + 8,  psB, hB);
    loadslot(e + 16, psC, hC);
    loadslot(e + 24, psD, hD);
    loadslot(e + 32, psE, hE);
    loadslot(e + 40, psF, hF);
    while (true) {
        if (e >= end) break;
        consume(psA, hA); loadslot(e + 48, psA, hA); e += 8;
        if (e >= end) break;
        consume(psB, hB); loadslot(e + 48, psB, hB); e += 8;
        if (e >= end) break;
        consume(psC, hC); loadslot(e + 48, psC, hC); e += 8;
        if (e >= end) break;
        consume(psD, hD); loadslot(e + 48, psD, hD); e += 8;
        if (e >= end) break;
        consume(psE, hE); loadslot(e + 48, psE, hE); e += 8;
        if (e >= end) break;
        consume(psF, hF); loadslot(e + 48, psF, hF); e += 8;
    }
    // den: sum over the 8 pairs, separately per parity (xor lane bits 1,2,3)
    den += __shfl_xor(den, 2, 64);
    den += __shfl_xor(den, 4, 64);
    den += __shfl_xor(den, 8, 64);
    // channel transpose-reduce via LDS (same-wave, no barrier needed)
    #pragma unroll
    for (int c = 0; c < 8; c++) sacc[t][c] = acc[c];
    float sum = 0.f;
    int rowb = g * 16 + (lane >> 3);     // parity row matching my channel's head
    int ch = lane & 7;
    #pragma unroll
    for (int pp = 0; pp < 8; pp++) sum += sacc[rowb + 2 * pp][ch];

    // fetch den for my head: lane (g*16 + head) holds head's den after reduce
    int wgbase = t & 0x30;
    float denh = __shfl(den, wgbase | (lane >> 3), 64);

    float o = sum / (denh + 1e-16f) + b1[lane];
    o = (o > 0.f) ? o : 0.f;                     // ReLU
    float v = o * W2[lane];                      // fused (16 -> 1) @W2
    v += __shfl_xor(v, 1, 64);
    v += __shfl_xor(v, 2, 64);
    v += __shfl_xor(v, 4, 64);
    v += __shfl_xor(v, 8, 64);
    if (lane == 0) h2out[d] = v;
}

// ------------- layer-2 edge pass (CSR walk, 6-deep pipeline) ----------
__global__ __launch_bounds__(256) void k_edge2(
        const int* __restrict__ offs, const uint2* __restrict__ csr8,
        const float* __restrict__ h2,
        const float* __restrict__ a_src2, const float* __restrict__ a_dst2,
        const float* __restrict__ b2, float* __restrict__ out) {
    int t = threadIdx.x;
    int g = t >> 4, lane = t & 15;
    int d = blockIdx.x * 16 + g;
    if (d >= N_NODES) return;

    float as2 = a_src2[0], ad2 = a_dst2[0];
    float adv = h2[d] * ad2;
    int beg = offs[d], end = offs[d + 1];

    float den = 0.f, acc = 0.f;
    auto ls = [&](int ee, float& hs) { if (ee < end) hs = h2[csr8[ee].y]; };
    auto cs = [&](float hs) {
        float a = fmaf(hs, as2, adv);
        a = (a > 0.f) ? a : 0.2f * a;
        float p = __expf(a);
        den += p;
        acc = fmaf(p, hs, acc);
    };
    float hA = 0.f, hB = 0.f, hC = 0.f, hD = 0.f, hE = 0.f, hF = 0.f;
    int e = beg + lane;
    ls(e, hA); ls(e + 16, hB); ls(e + 32, hC);
    ls(e + 48, hD); ls(e + 64, hE); ls(e + 80, hF);
    while (true) {
        if (e >= end) break;
        cs(hA); ls(e + 96, hA); e += 16;
        if (e >= end) break;
        cs(hB); ls(e + 96, hB); e += 16;
        if (e >= end) break;
        cs(hC); ls(e + 96, hC); e += 16;
        if (e >= end) break;
        cs(hD); ls(e + 96, hD); e += 16;
        if (e >= end) break;
        cs(hE); ls(e + 96, hE); e += 16;
        if (e >= end) break;
        cs(hF); ls(e + 96, hF); e += 16;
    }
    #pragma unroll
    for (int m = 1; m < 16; m <<= 1) {
        den += __shfl_xor(den, m, 64);
        acc += __shfl_xor(acc, m, 64);
    }
    if (lane == 0) out[d] = acc / (den + 1e-16f) + b2[0];
}

// ---------------- launch ----------------
extern "C" void kernel_launch(void* const* d_in, const int* in_sizes, int n_in,
                              void* d_out, int out_size, void* d_ws, size_t ws_size,
                              hipStream_t stream) {
    const float* x      = (const float*)d_in[0];
    const int*   edge   = (const int*)  d_in[1];
    const float* W1     = (const float*)d_in[2];
    const float* a_src1 = (const float*)d_in[3];
    const float* a_dst1 = (const float*)d_in[4];
    const float* b1     = (const float*)d_in[5];
    const float* W2     = (const float*)d_in[6];
    const float* a_src2 = (const float*)d_in[7];
    const float* a_dst2 = (const float*)d_in[8];
    const float* b2     = (const float*)d_in[9];

    constexpr size_t A = 256;
    auto al = [](size_t b) { return (b + A - 1) / A * A; };
    char* ws = (char*)d_ws;
    size_t off = 0;
    int*      flag   = (int*)(ws + off);      off += al(256);
    int*      ccnt   = (int*)(ws + off);      off += al((size_t)NCHUNK * NBUCK * 4); // 830 KB
    int*      bcnt   = (int*)(ws + off);      off += al(NBUCK * 4);
    int*      bbase  = (int*)(ws + off);      off += al((NBUCK + 1) * 4);
    unsigned* staged = (unsigned*)(ws + off); off += al((size_t)E_TOT * 4);          // 26 MB
    uint2*    csr8   = (uint2*)(ws + off);    off += al((size_t)E_TOT * 8);          // 52 MB
    int*      offs   = (int*)(ws + off);      off += al((size_t)(N_NODES + 1) * 4);
    __half*   h16    = (__half*)(ws + off);   off += al((size_t)N_NODES * NHID * 2); // 3.2 MB
    float*    asrc   = (float*)(ws + off);    off += al((size_t)N_NODES * 2 * 4);    // 0.8 MB
    float*    adst   = (float*)(ws + off);    off += al((size_t)N_NODES * 2 * 4);    // 0.8 MB
    float*    h2     = (float*)(ws + off);    off += al((size_t)N_NODES * 4);
    (void)ws_size; (void)in_sizes; (void)n_in; (void)out_size;

    k_detect<<<1, 64, 0, stream>>>(edge, flag);
    k_gemm1 <<<(N_NODES + 15) / 16, 256, 0, stream>>>(x, W1, a_src1, a_dst1, h16, asrc, adst);
    k_ccount<<<NCHUNK, 256, 0, stream>>>(edge, flag, ccnt);
    k_cscan <<<NBUCK, 256, 0, stream>>>(ccnt, bcnt);
    k_bscan <<<1, 256, 0, stream>>>(bcnt, bbase);
    k_bin   <<<NCHUNK, 256, 0, stream>>>(edge, flag, ccnt, bbase, staged);
    k_sort  <<<NBUCK * 2, 1024, 0, stream>>>(staged, bbase, asrc, adst, csr8, offs);
    k_edge1 <<<(N_NODES + 15) / 16, 256, 0, stream>>>(offs, csr8, h16, b1, W2, h2);
    k_edge2 <<<(N_NODES + 15) / 16, 256, 0, stream>>>(offs, csr8, h2, a_src2, a_dst2, b2,
                                                      (float*)d_out);
}

// Round 11
// 232.294 us; speedup vs baseline: 1.0071x; 1.0071x over previous
//
#include <hip/hip_runtime.h>
#include <hip/hip_fp16.h>
#include <cstdint>
#include <cstddef>

#define N_NODES 100000
#define E_EDGES 6400000
#define E_TOT   (E_EDGES + N_NODES)
#define IN_CH   128
#define NHID    16              // HEADS*HID
#define BSHIFT  9               // 512 dsts per bucket
#define BSZ     512
#define NBUCK   196             // ceil(100000/512)
#define CHUNK   6144            // edges per k_bin block
#define BCAP    48              // LDS staging capacity per bucket (mean 31.3)
#define NCHUNK  ((E_TOT + CHUNK - 1) / CHUNK)   // 1058

// ---------------- detection: int64 vs int32 edge_index ----------------
__global__ void k_detect(const int* __restrict__ edge, int* __restrict__ flag) {
    if (blockIdx.x == 0 && threadIdx.x == 0) {
        int odd_or = 0;
        for (int i = 0; i < 64; i++) odd_or |= edge[2 * i + 1];
        flag[0] = (odd_or == 0) ? 1 : 0;   // 1 => data is int64 little-endian
    }
}

// ------- layer-1 node features: h16 rows + split alpha arrays ---------
__global__ __launch_bounds__(256) void k_gemm1(
        const float* __restrict__ x, const float* __restrict__ W1,
        const float* __restrict__ a_src1, const float* __restrict__ a_dst1,
        __half* __restrict__ h16, float* __restrict__ asrc,
        float* __restrict__ adst) {
    __shared__ __align__(16) float sW[IN_CH * NHID];   // 8 KB
    __shared__ __align__(16) float sx[16][132];        // padded stride
    __shared__ float sh[16][17];
    int t = threadIdx.x;
    int r = t >> 4, c = t & 15;
    int row = blockIdx.x * 16 + r;

    const float4* W4 = (const float4*)W1;
    ((float4*)sW)[t] = W4[t];
    ((float4*)sW)[t + 256] = W4[t + 256];

    if (row < N_NODES) {
        const float4* xr = (const float4*)(x + (size_t)row * IN_CH);
        float4 v0 = xr[c];
        float4 v1 = xr[c + 16];
        *(float4*)&sx[r][4 * c] = v0;
        *(float4*)&sx[r][64 + 4 * c] = v1;
    }
    __syncthreads();

    float acc = 0.f;
    if (row < N_NODES) {
        #pragma unroll 16
        for (int k = 0; k < IN_CH; k++) acc = fmaf(sx[r][k], sW[k * NHID + c], acc);
        h16[(size_t)row * NHID + c] = __float2half(acc);
    }
    sh[r][c] = acc;
    __syncthreads();

    if (row < N_NODES && c < 4) {
        int h = c & 1;
        const float* av = (c >= 2) ? a_dst1 : a_src1;
        float s = 0.f;
        #pragma unroll
        for (int q = 0; q < 8; q++) s = fmaf(sh[r][h * 8 + q], av[h * 8 + q], s);
        if (c < 2) asrc[2 * (size_t)row + c] = s;
        else       adst[2 * (size_t)row + (c - 2)] = s;
    }
}

// --- per-chunk 196-bucket histogram; int4-vectorized edge reads -------
__global__ __launch_bounds__(256) void k_ccount(const int* __restrict__ edge,
                                                const int* __restrict__ flag,
                                                int* __restrict__ ccnt) {
    __shared__ int sc[NBUCK];
    int m64 = flag[0];
    int t = threadIdx.x;
    for (int i = t; i < NBUCK; i += 256) sc[i] = 0;
    __syncthreads();
    size_t c0 = (size_t)blockIdx.x * CHUNK;
    size_t cend = c0 + CHUNK; if (cend > E_TOT) cend = E_TOT;
    size_t ee = (cend < (size_t)E_EDGES) ? cend : (size_t)E_EDGES;

    if (m64) {
        const int4* dp = (const int4*)(edge + 2 * (size_t)E_EDGES);
        for (size_t i = c0 + 2 * t; i < ee; i += 512) {
            int4 v = dp[i >> 1];                 // dsts of edges i, i+1
            atomicAdd(&sc[v.x >> BSHIFT], 1);
            if (i + 1 < ee) atomicAdd(&sc[v.z >> BSHIFT], 1);
        }
    } else {
        const int4* dp = (const int4*)(edge + (size_t)E_EDGES);
        for (size_t i = c0 + 4 * t; i < ee; i += 1024) {
            int4 v = dp[i >> 2];                 // dsts of edges i..i+3
            atomicAdd(&sc[v.x >> BSHIFT], 1);
            if (i + 1 < ee) atomicAdd(&sc[v.y >> BSHIFT], 1);
            if (i + 2 < ee) atomicAdd(&sc[v.z >> BSHIFT], 1);
            if (i + 3 < ee) atomicAdd(&sc[v.w >> BSHIFT], 1);
        }
    }
    size_t sl0 = (c0 > (size_t)E_EDGES) ? c0 : (size_t)E_EDGES;
    for (size_t i = sl0 + t; i < cend; i += 256) {
        int d = (int)(i - E_EDGES);              // self-loop: no memory read
        atomicAdd(&sc[d >> BSHIFT], 1);
    }
    __syncthreads();
    for (int i = t; i < NBUCK; i += 256)
        ccnt[(size_t)blockIdx.x * NBUCK + i] = sc[i];
}

// --- per-bucket exclusive scan over chunks: exact per-chunk bases -----
__global__ __launch_bounds__(256) void k_cscan(int* __restrict__ ccnt,
                                               int* __restrict__ bcnt) {
    __shared__ int sd[256];
    __shared__ int carry;
    int b = blockIdx.x, t = threadIdx.x;
    if (t == 0) carry = 0;
    __syncthreads();
    for (int base = 0; base < NCHUNK; base += 256) {
        int c = base + t;
        int v = (c < NCHUNK) ? ccnt[(size_t)c * NBUCK + b] : 0;
        sd[t] = v;
        __syncthreads();
        for (int ofs = 1; ofs < 256; ofs <<= 1) {
            int a = sd[t];
            int bb = (t >= ofs) ? sd[t - ofs] : 0;
            __syncthreads();
            sd[t] = a + bb;
            __syncthreads();
        }
        if (c < NCHUNK) ccnt[(size_t)c * NBUCK + b] = sd[t] - v + carry;
        __syncthreads();
        if (t == 255) carry += sd[255];
        __syncthreads();
    }
    if (t == 0) bcnt[b] = carry;
}

// ---------------- tiny scan over 196 bucket totals ----------------
__global__ void k_bscan(const int* __restrict__ bcnt, int* __restrict__ bbase) {
    __shared__ int sd[256];
    int t = threadIdx.x;
    int v = (t < NBUCK) ? bcnt[t] : 0;
    sd[t] = v;
    __syncthreads();
    for (int ofs = 1; ofs < 256; ofs <<= 1) {
        int a = sd[t];
        int b = (t >= ofs) ? sd[t - ofs] : 0;
        __syncthreads();
        sd[t] = a + b;
        __syncthreads();
    }
    if (t < NBUCK) bbase[t] = sd[t] - v;        // exclusive
    if (t == NBUCK) bbase[NBUCK] = sd[NBUCK - 1];
}

// ------ binning with precomputed exact slots: ZERO global atomics -----
__global__ __launch_bounds__(256) void k_bin(const int* __restrict__ edge,
                                             const int* __restrict__ flag,
                                             const int* __restrict__ ccnt,
                                             const int* __restrict__ bbase,
                                             unsigned* __restrict__ staged) {
    __shared__ unsigned lbin[NBUCK][BCAP];   // 37.6 KB -> 4 blocks/CU
    __shared__ int lcnt[NBUCK];
    __shared__ int lbase[NBUCK];
    int m64 = flag[0];
    int t = threadIdx.x;
    int g = t >> 4, lane = t & 15;

    size_t c0 = (size_t)blockIdx.x * CHUNK;
    if (c0 >= E_TOT) return;
    size_t cend = c0 + CHUNK; if (cend > E_TOT) cend = E_TOT;
    size_t ee = (cend < (size_t)E_EDGES) ? cend : (size_t)E_EDGES;

    for (int i = t; i < NBUCK; i += 256) {
        lcnt[i] = 0;
        lbase[i] = bbase[i] + ccnt[(size_t)blockIdx.x * NBUCK + i];
    }
    __syncthreads();

    auto put = [&](int s, int d) {
        int b = d >> BSHIFT;
        unsigned v = (unsigned)s | ((unsigned)(d & (BSZ - 1)) << 17);
        int idx = atomicAdd(&lcnt[b], 1);
        if (idx < BCAP) lbin[b][idx] = v;
        else            staged[lbase[b] + idx] = v;   // exact slot, no atomic
    };

    if (m64) {
        const int4* sp = (const int4*)edge;
        const int4* dp = (const int4*)(edge + 2 * (size_t)E_EDGES);
        for (size_t i = c0 + 2 * t; i < ee; i += 512) {
            int4 sv = sp[i >> 1];
            int4 dv = dp[i >> 1];
            put(sv.x, dv.x);
            if (i + 1 < ee) put(sv.z, dv.z);
        }
    } else {
        const int4* sp = (const int4*)edge;
        const int4* dp = (const int4*)(edge + (size_t)E_EDGES);
        for (size_t i = c0 + 4 * t; i < ee; i += 1024) {
            int4 sv = sp[i >> 2];
            int4 dv = dp[i >> 2];
            put(sv.x, dv.x);
            if (i + 1 < ee) put(sv.y, dv.y);
            if (i + 2 < ee) put(sv.z, dv.z);
            if (i + 3 < ee) put(sv.w, dv.w);
        }
    }
    size_t sl0 = (c0 > (size_t)E_EDGES) ? c0 : (size_t)E_EDGES;
    for (size_t i = sl0 + t; i < cend; i += 256) {
        int d = (int)(i - E_EDGES);
        put(d, d);
    }
    __syncthreads();
    // cooperative coalesced flush of the LDS-staged majority
    for (int b = g; b < NBUCK; b += 16) {
        int n = min(lcnt[b], BCAP);
        if (!n) continue;
        int pos = lbase[b];
        for (int i = lane; i < n; i += 16) staged[pos + i] = lbin[b][i];
    }
}

// -- per-bucket counting sort -> CSR; 2 blocks/bucket (edge-range split)
__global__ __launch_bounds__(1024) void k_sort(const unsigned* __restrict__ staged,
                                               const int* __restrict__ bbase,
                                               int* __restrict__ csr,
                                               int* __restrict__ offs) {
    __shared__ int hist[BSZ];
    __shared__ int histlo[BSZ];
    __shared__ int lcur[BSZ];
    int bkt = blockIdx.x >> 1, p = blockIdx.x & 1;
    int t = threadIdx.x;
    int beg = bbase[bkt], end = bbase[bkt + 1];
    int mid = beg + ((end - beg + 1) >> 1);
    int dbase = bkt << BSHIFT;

    if (t < BSZ) { hist[t] = 0; histlo[t] = 0; }
    __syncthreads();
    for (int e = beg + t; e < end; e += 1024) {
        int dl = staged[e] >> 17;
        atomicAdd(&hist[dl], 1);
        if (e < mid) atomicAdd(&histlo[dl], 1);
    }
    __syncthreads();

    int myv = (t < BSZ) ? hist[t] : 0;
    __syncthreads();
    for (int ofs = 1; ofs < BSZ; ofs <<= 1) {
        int a = 0, b = 0;
        if (t < BSZ) { a = hist[t]; b = (t >= ofs) ? hist[t - ofs] : 0; }
        __syncthreads();
        if (t < BSZ) hist[t] = a + b;
        __syncthreads();
    }
    if (t < BSZ) {
        int excl = hist[t] - myv;
        lcur[t] = excl + (p ? histlo[t] : 0);
        if (p == 0) {
            int dd = dbase + t;
            if (dd < N_NODES) offs[dd] = beg + excl;
        }
    }
    if (bkt == NBUCK - 1 && p == 0 && t == 0) offs[N_NODES] = E_TOT;
    __syncthreads();

    int lo = p ? mid : beg;
    int hi = p ? end : mid;
    for (int e = lo + t; e < hi; e += 1024) {
        unsigned v = staged[e];
        int pos = atomicAdd(&lcur[v >> 17], 1);
        csr[beg + pos] = (int)(v & 0x1FFFFu);   // 133 KB window: L2-resident
    }
}

// --- layer-1 edge pass: pair-lane (2 lanes/edge), 6-deep pipeline -----
// Pair shares one merged asrc txn + one h-row line txn; each lane does
// ONE exp (its own head). Gather set = h16 3.2MB + asrc 0.8MB: both
// XCD-L2-resident. p never round-trips through memory.
__global__ __launch_bounds__(256) void k_edge1(
        const int* __restrict__ offs, const int* __restrict__ csr,
        const __half* __restrict__ h16, const float* __restrict__ asrc,
        const float* __restrict__ adst,
        const float* __restrict__ b1, const float* __restrict__ W2,
        float* __restrict__ h2out) {
    __shared__ float sacc[256][9];   // 9 KB, padded
    int t = threadIdx.x;
    int lane = t & 15;
    int g = t >> 4;
    int d = blockIdx.x * 16 + g;
    if (d >= N_NODES) return;

    int sub = lane & 1;        // 0: head0/ch0-7, 1: head1/ch8-15
    int pr  = lane >> 1;       // pair index 0..7
    float2 adp = ((const float2*)adst)[d];
    float adpv = sub ? adp.y : adp.x;
    int beg = offs[d], end = offs[d + 1];

    float acc[8];
    #pragma unroll
    for (int c = 0; c < 8; c++) acc[c] = 0.f;
    float den = 0.f;

    auto loadslot = [&](int ee, float& aspv, float4& hv) {
        if (ee < end) {
            int s = csr[ee];
            float2 asp = ((const float2*)asrc)[s];   // pair: same addr, 1 txn
            aspv = sub ? asp.y : asp.x;
            hv = *(const float4*)(h16 + (size_t)s * NHID + sub * 8);
        }
    };
    auto consume = [&](float aspv, const float4& hv) {
        float a = aspv + adpv; a = (a > 0.f) ? a : 0.2f * a;
        float pw = __expf(a);
        den += pw;
        const __half2* hh = (const __half2*)&hv;
        #pragma unroll
        for (int q = 0; q < 4; q++) {
            float2 f = __half22float2(hh[q]);
            acc[2 * q]     = fmaf(pw, f.x, acc[2 * q]);
            acc[2 * q + 1] = fmaf(pw, f.y, acc[2 * q + 1]);
        }
    };

    float aA = 0.f, aB = 0.f, aC = 0.f, aD = 0.f, aE = 0.f, aF = 0.f;
    float4 z4 = make_float4(0.f, 0.f, 0.f, 0.f);
    float4 hA = z4, hB = z4, hC = z4, hD = z4, hE = z4, hF = z4;

    int e = beg + pr;
    loadslot(e,      aA, hA);
    loadslot(e + 8,  aB, hB);
    loadslot(e + 16, aC, hC);
    loadslot(e + 24, aD, hD);
    loadslot(e + 32, aE, hE);
    loadslot(e + 40, aF, hF);
    while (true) {
        if (e >= end) break;
        consume(aA, hA); loadslot(e + 48, aA, hA); e += 8;
        if (e >= end) break;
        consume(aB, hB); loadslot(e + 48, aB, hB); e += 8;
        if (e >= end) break;
        consume(aC, hC); loadslot(e + 48, aC, hC); e += 8;
        if (e >= end) break;
        consume(aD, hD); loadslot(e + 48, aD, hD); e += 8;
        if (e >= end) break;
        consume(aE, hE); loadslot(e + 48, aE, hE); e += 8;
        if (e >= end) break;
        consume(aF, hF); loadslot(e + 48, aF, hF); e += 8;
    }
    // den: sum across the 8 pairs, per parity (xor lane bits 1..3)
    den += __shfl_xor(den, 2, 64);
    den += __shfl_xor(den, 4, 64);
    den += __shfl_xor(den, 8, 64);
    // channel transpose-reduce via LDS (same-wave, no barrier needed)
    #pragma unroll
    for (int c = 0; c < 8; c++) sacc[t][c] = acc[c];
    float sum = 0.f;
    int rowb = g * 16 + (lane >> 3);     // parity row matching my channel's head
    int ch = lane & 7;
    #pragma unroll
    for (int pp = 0; pp < 8; pp++) sum += sacc[rowb + 2 * pp][ch];

    // fetch den for my head: lane (wgbase + head) holds that head's den
    int wgbase = t & 0x30;
    float denh = __shfl(den, wgbase | (lane >> 3), 64);

    float o = sum / (denh + 1e-16f) + b1[lane];
    o = (o > 0.f) ? o : 0.f;                     // ReLU
    float v = o * W2[lane];                      // fused (16 -> 1) @W2
    v += __shfl_xor(v, 1, 64);
    v += __shfl_xor(v, 2, 64);
    v += __shfl_xor(v, 4, 64);
    v += __shfl_xor(v, 8, 64);
    if (lane == 0) h2out[d] = v;
}

// ------------- layer-2 edge pass (CSR walk, 6-deep pipeline) ----------
__global__ __launch_bounds__(256) void k_edge2(
        const int* __restrict__ offs, const int* __restrict__ csr,
        const float* __restrict__ h2,
        const float* __restrict__ a_src2, const float* __restrict__ a_dst2,
        const float* __restrict__ b2, float* __restrict__ out) {
    int t = threadIdx.x;
    int g = t >> 4, lane = t & 15;
    int d = blockIdx.x * 16 + g;
    if (d >= N_NODES) return;

    float as2 = a_src2[0], ad2 = a_dst2[0];
    float adv = h2[d] * ad2;
    int beg = offs[d], end = offs[d + 1];

    float den = 0.f, acc = 0.f;
    auto ls = [&](int ee, float& hs) { if (ee < end) hs = h2[csr[ee]]; };
    auto cs = [&](float hs) {
        float a = fmaf(hs, as2, adv);
        a = (a > 0.f) ? a : 0.2f * a;
        float p = __expf(a);
        den += p;
        acc = fmaf(p, hs, acc);
    };
    float hA = 0.f, hB = 0.f, hC = 0.f, hD = 0.f, hE = 0.f, hF = 0.f;
    int e = beg + lane;
    ls(e, hA); ls(e + 16, hB); ls(e + 32, hC);
    ls(e + 48, hD); ls(e + 64, hE); ls(e + 80, hF);
    while (true) {
        if (e >= end) break;
        cs(hA); ls(e + 96, hA); e += 16;
        if (e >= end) break;
        cs(hB); ls(e + 96, hB); e += 16;
        if (e >= end) break;
        cs(hC); ls(e + 96, hC); e += 16;
        if (e >= end) break;
        cs(hD); ls(e + 96, hD); e += 16;
        if (e >= end) break;
        cs(hE); ls(e + 96, hE); e += 16;
        if (e >= end) break;
        cs(hF); ls(e + 96, hF); e += 16;
    }
    #pragma unroll
    for (int m = 1; m < 16; m <<= 1) {
        den += __shfl_xor(den, m, 64);
        acc += __shfl_xor(acc, m, 64);
    }
    if (lane == 0) out[d] = acc / (den + 1e-16f) + b2[0];
}

// ---------------- launch ----------------
extern "C" void kernel_launch(void* const* d_in, const int* in_sizes, int n_in,
                              void* d_out, int out_size, void* d_ws, size_t ws_size,
                              hipStream_t stream) {
    const float* x      = (const float*)d_in[0];
    const int*   edge   = (const int*)  d_in[1];
    const float* W1     = (const float*)d_in[2];
    const float* a_src1 = (const float*)d_in[3];
    const float* a_dst1 = (const float*)d_in[4];
    const float* b1     = (const float*)d_in[5];
    const float* W2     = (const float*)d_in[6];
    const float* a_src2 = (const float*)d_in[7];
    const float* a_dst2 = (const float*)d_in[8];
    const float* b2     = (const float*)d_in[9];

    constexpr size_t A = 256;
    auto al = [](size_t b) { return (b + A - 1) / A * A; };
    char* ws = (char*)d_ws;
    size_t off = 0;
    int*      flag   = (int*)(ws + off);      off += al(256);
    int*      ccnt   = (int*)(ws + off);      off += al((size_t)NCHUNK * NBUCK * 4); // 830 KB
    int*      bcnt   = (int*)(ws + off);      off += al(NBUCK * 4);
    int*      bbase  = (int*)(ws + off);      off += al((NBUCK + 1) * 4);
    unsigned* staged = (unsigned*)(ws + off); off += al((size_t)E_TOT * 4);          // 26 MB
    int*      csr    = (int*)(ws + off);      off += al((size_t)E_TOT * 4);          // 26 MB
    int*      offs   = (int*)(ws + off);      off += al((size_t)(N_NODES + 1) * 4);
    __half*   h16    = (__half*)(ws + off);   off += al((size_t)N_NODES * NHID * 2); // 3.2 MB
    float*    asrc   = (float*)(ws + off);    off += al((size_t)N_NODES * 2 * 4);    // 0.8 MB
    float*    adst   = (float*)(ws + off);    off += al((size_t)N_NODES * 2 * 4);    // 0.8 MB
    float*    h2     = (float*)(ws + off);    off += al((size_t)N_NODES * 4);
    (void)ws_size; (void)in_sizes; (void)n_in; (void)out_size;

    k_detect<<<1, 64, 0, stream>>>(edge, flag);
    k_gemm1 <<<(N_NODES + 15) / 16, 256, 0, stream>>>(x, W1, a_src1, a_dst1, h16, asrc, adst);
    k_ccount<<<NCHUNK, 256, 0, stream>>>(edge, flag, ccnt);
    k_cscan <<<NBUCK, 256, 0, stream>>>(ccnt, bcnt);
    k_bscan <<<1, 256, 0, stream>>>(bcnt, bbase);
    k_bin   <<<NCHUNK, 256, 0, stream>>>(edge, flag, ccnt, bbase, staged);
    k_sort  <<<NBUCK * 2, 1024, 0, stream>>>(staged, bbase, csr, offs);
    k_edge1 <<<(N_NODES + 15) / 16, 256, 0, stream>>>(offs, csr, h16, asrc, adst, b1, W2, h2);
    k_edge2 <<<(N_NODES + 15) / 16, 256, 0, stream>>>(offs, csr, h2, a_src2, a_dst2, b2,
                                                      (float*)d_out);
}